// Round 4
// baseline (6631.210 us; speedup 1.0000x reference)
//
#include <hip/hip_runtime.h>
#include <math.h>

// CapsuleLayer dynamic routing, MI355X fp32. Round 6: LDS-staged W (coalescing).
// B=64, In=2048, Din=16, Nc=32, Dc=32, ROUTINGS=3.
// Identity: b starts at 0 => logits_t = hat . (v1+..+v_{t-1}); never store b or hat.
//
// Round-5 post-mortem: spills fixed (WRITE 46MB) but still 212us/pass at
// VALUBusy 27%, occ 22%, HBM 8%. Cause: per-thread-private W rows make every
// vector load touch 64 distinct cache lines (16B/lane at 256B stride) ->
// ~262k cycles/CU of L1 transaction occupancy. Fix: redistribute W through LDS.
//  - global_load_lds, 1KB/instr fully coalesced (8 lines/instr, 8x fewer).
//  - d-quarter tiles [32j][8d][16k] = 16KB, ping-pong dbuf, stage-ahead-2,
//    one __syncthreads per quarter (issue stage -> compute -> drain at barrier).
//  - XOR swizzle chunk ^= (chunk>>3)&7 (involution): applied on the global
//    source (linear LDS dest), inverse on ds_read -> 8 lanes/slot, conflict-free.
//  - Thread (j=t>>3, dL=t&7) owns d = {dL, dL+8, dL+16, dL+24}; acc[8b][4r].
//  - Phase 1: hat in regs; vsum preloaded to 32 regs ONCE (no per-il v loads);
//    softmax exchange via c_s dbuf + lgkm-only barriers (proven r5).
//  - LDS 42KB -> 3 blocks/CU (12 waves). launch_bounds(256,2) (no VGPR squeeze).

#define B_TOT   64
#define IN_CAPS 2048
#define DIN     16
#define NC      32
#define DC      32
#define JD      (NC * DC)            // 1024
#define B_CHUNK 8
#define I_CHUNK 16
#define N_IG    (IN_CAPS / I_CHUNK)  // 128
#define N_BG    (B_TOT / B_CHUNK)    // 8
#define EPS_SQ  1e-7f

__device__ __forceinline__ float dot4(const float4 a, const float4 b) {
    return a.x*b.x + a.y*b.y + a.z*b.z + a.w*b.w;
}

// Raw workgroup barrier: drain LDS ops only (no vmcnt) -> W-stage loads survive.
#define LDS_BARRIER() do {                                  \
    asm volatile("" ::: "memory");                          \
    asm volatile("s_waitcnt lgkmcnt(0)");                   \
    __builtin_amdgcn_s_barrier();                           \
    asm volatile("" ::: "memory");                          \
} while (0)

// Stage one d-quarter tile (32 j x 8 d x 16 k = 16KB = 1024 chunks of 16B)
// for input capsule i into wbuf. One instr covers 1KB = a j-PAIR's 512B halves;
// wave w issues 4 instrs (j-pairs w*4..w*4+3). LDS dest is linear
// (base + lane*16, HW rule); the swizzle is pre-applied on the global source:
// physical chunk p = j*32+l5 holds logical chunk p ^ ((p>>3)&7).
__device__ __forceinline__ void stage_quarter(float4* wbuf,
                                              const float4* __restrict__ Wf4,
                                              int i, int Q, int wave, int lane)
{
    const int l5   = lane & 31;
    const int jodd = lane >> 5;
#pragma unroll
    for (int q = 0; q < 4; ++q) {
        const int jp = wave * 4 + q;          // j-pair 0..15
        const int j  = jp * 2 + jodd;
        const int src_loc = l5 ^ (((j & 1) << 2) | (l5 >> 3));  // l5>>3 in 0..3
        const float4* g = Wf4 + ((size_t)j * IN_CAPS + i) * 128 + Q * 32 + src_loc;
        __builtin_amdgcn_global_load_lds(
            (const __attribute__((address_space(1))) void*)g,
            (__attribute__((address_space(3))) void*)(wbuf + jp * 64),
            16, 0, 0);
    }
}

// Compute one quarter: row d = 8*Q + dL, all 16 k, 8 batches.
// Read swizzle: physical chunk = (j*32 + dL*4 + k4) ^ (((j&1)<<2) | (dL>>1)).
template <int PHASE, int Q>
__device__ __forceinline__ void compute_quarter(
    const float4* __restrict__ wbuf,
    const float4 (*__restrict__ xsil)[DIN / 4],
    int j, int dL, float (*__restrict__ acc)[4], float (*__restrict__ h)[4])
{
    const int cbase = j * 32 + dL * 4;
    const int key   = ((j & 1) << 2) | (dL >> 1);
    float4 w[4];
#pragma unroll
    for (int k4 = 0; k4 < 4; ++k4)
        w[k4] = wbuf[(cbase + k4) ^ key];
#pragma unroll
    for (int b = 0; b < B_CHUNK; ++b) {
        float s = 0.f;
#pragma unroll
        for (int k4 = 0; k4 < 4; ++k4)
            s += dot4(w[k4], xsil[b][k4]);   // xsil: block-uniform broadcast
        if (PHASE == 0) acc[b][Q] += s;
        else            h[b][Q] = s;
    }
}

// PHASE 0: c = 1/32 uniform (softmax of zeros), plain sum.
// PHASE 1: logits = hat . vsum, softmax over j, weighted sum.
template <int PHASE, int ATOMIC>
__launch_bounds__(256, 2)
__global__ void caps_pass(const float* __restrict__ x,
                          const float* __restrict__ W,
                          const float* __restrict__ vsum,
                          float* __restrict__ P)
{
    __shared__ float4 wtile[2][1024];                    // 32 KB (2 x 16KB dbuf)
    __shared__ float4 xs4[I_CHUNK][B_CHUNK][DIN / 4];    // 8 KB
    __shared__ float  c_s[2][B_CHUNK][NC];               // 2 KB

    const int t    = threadIdx.x;
    const int wave = t >> 6;
    const int lane = t & 63;
    const int j    = t >> 3;                // 0..31 output capsule
    const int dL   = t & 7;                 // row-in-quarter

    // XCD-clustered swizzle: 8 bg-siblings of one ig adjacent on one XCD.
    const int r   = blockIdx.x;             // 0..1023
    const int xcd = r & 7;
    const int s   = r >> 3;
    const int bg  = s & 7;
    const int ig  = (s >> 3) * 8 + xcd;
    const int b0  = bg * B_CHUNK;
    const int i0  = ig * I_CHUNK;

    const float4* Wf4 = (const float4*)W;

    // ---- x staging (reg->LDS, once) ----
    float4 sx[2];
    int il_s[2], bl_s[2], k4_s[2];
#pragma unroll
    for (int q = 0; q < 2; ++q) {
        const int f = t * 2 + q;            // 512 float4
        il_s[q] = f >> 5;
        bl_s[q] = (f >> 2) & 7;
        k4_s[q] = f & 3;
        sx[q] = *(const float4*)
            &x[((size_t)(b0 + bl_s[q]) * IN_CAPS + (i0 + il_s[q])) * DIN + k4_s[q] * 4];
    }

    // ---- vsum fragments, loaded ONCE per pass (phase 1) ----
    float vr[B_CHUNK][4];
    if (PHASE) {
#pragma unroll
        for (int b = 0; b < B_CHUNK; ++b)
#pragma unroll
            for (int q = 0; q < 4; ++q)
                vr[b][q] = vsum[(size_t)(b0 + b) * JD + j * DC + 8 * q + dL];
    }

#pragma unroll
    for (int q = 0; q < 2; ++q) xs4[il_s[q]][bl_s[q]][k4_s[q]] = sx[q];

    // prologue: stage quarters 0,1 of il=0
    stage_quarter(&wtile[0][0], Wf4, i0, 0, wave, lane);
    stage_quarter(&wtile[1][0], Wf4, i0, 1, wave, lane);
    __syncthreads();

    float acc[B_CHUNK][4];
#pragma unroll
    for (int b = 0; b < B_CHUNK; ++b)
#pragma unroll
        for (int dd = 0; dd < 4; ++dd) acc[b][dd] = 0.f;

    float h[B_CHUNK][4];

#pragma unroll 1
    for (int il = 0; il < I_CHUNK; ++il) {
        const float4 (*__restrict__ xsil)[DIN / 4] = xs4[il];
        const int i = i0 + il;

        compute_quarter<PHASE, 0>(&wtile[0][0], xsil, j, dL, acc, h);
        __syncthreads();                               // all read buf0; Q1 ready
        stage_quarter(&wtile[0][0], Wf4, i, 2, wave, lane);

        compute_quarter<PHASE, 1>(&wtile[1][0], xsil, j, dL, acc, h);
        __syncthreads();                               // all read buf1; Q2 ready
        stage_quarter(&wtile[1][0], Wf4, i, 3, wave, lane);

        compute_quarter<PHASE, 2>(&wtile[0][0], xsil, j, dL, acc, h);
        __syncthreads();                               // all read buf0; Q3 ready
        if (il + 1 < I_CHUNK)
            stage_quarter(&wtile[0][0], Wf4, i + 1, 0, wave, lane);

        compute_quarter<PHASE, 3>(&wtile[1][0], xsil, j, dL, acc, h);

        if (PHASE == 1) {
            const int buf = il & 1;
            // logits: full-d dot = reduce over the 8 dL-lanes sharing j
            float lp[B_CHUNK];
#pragma unroll
            for (int b = 0; b < B_CHUNK; ++b) {
                lp[b] = h[b][0]*vr[b][0] + h[b][1]*vr[b][1]
                      + h[b][2]*vr[b][2] + h[b][3]*vr[b][3];
                lp[b] += __shfl_xor(lp[b], 1, 8);
                lp[b] += __shfl_xor(lp[b], 2, 8);
                lp[b] += __shfl_xor(lp[b], 4, 8);
            }
            if (dL == 0) {
#pragma unroll
                for (int b = 0; b < B_CHUNK; ++b) c_s[buf][b][j] = lp[b];
            }
            LDS_BARRIER();
            // softmax over j: one thread per (b, j), width-32 butterflies
            {
                const int tb = t >> 5, tj = t & 31;
                const float l = c_s[buf][tb][tj];
                float m = l;
                m = fmaxf(m, __shfl_xor(m, 1, 32));
                m = fmaxf(m, __shfl_xor(m, 2, 32));
                m = fmaxf(m, __shfl_xor(m, 4, 32));
                m = fmaxf(m, __shfl_xor(m, 8, 32));
                m = fmaxf(m, __shfl_xor(m, 16, 32));
                const float e = __expf(l - m);
                float ss = e;
                ss += __shfl_xor(ss, 1, 32);
                ss += __shfl_xor(ss, 2, 32);
                ss += __shfl_xor(ss, 4, 32);
                ss += __shfl_xor(ss, 8, 32);
                ss += __shfl_xor(ss, 16, 32);
                c_s[buf][tb][tj] = e / ss;
            }
            LDS_BARRIER();
#pragma unroll
            for (int b = 0; b < B_CHUNK; ++b) {
                const float c = c_s[buf][b][j];       // broadcast
                acc[b][0] += c * h[b][0];
                acc[b][1] += c * h[b][1];
                acc[b][2] += c * h[b][2];
                acc[b][3] += c * h[b][3];
            }
        }

        __syncthreads();                               // all read buf1
        if (il + 1 < I_CHUNK)
            stage_quarter(&wtile[1][0], Wf4, i + 1, 1, wave, lane);
    }

    const float scale = (PHASE == 0) ? (1.f / NC) : 1.f;
    if (ATOMIC) {
#pragma unroll
        for (int b = 0; b < B_CHUNK; ++b)
#pragma unroll
            for (int q = 0; q < 4; ++q)
                atomicAdd(&P[(size_t)(b0 + b) * JD + j * DC + 8 * q + dL],
                          acc[b][q] * scale);
    } else {
        float* dstp = P + ((size_t)ig * B_TOT + b0) * JD + j * DC + dL;
#pragma unroll
        for (int b = 0; b < B_CHUNK; ++b)
#pragma unroll
            for (int q = 0; q < 4; ++q)
                dstp[(size_t)b * JD + 8 * q] = acc[b][q] * scale;
    }
}

// Sum nparts partials (float4), squash over Dc=32 (8 consecutive lanes = one
// capsule), then: mode 0: VSUM = v ; mode 1: VSUM += v ; mode 2: OUT = v
__global__ void reduce_squash(const float* __restrict__ Pf, int nparts,
                              float* __restrict__ VSUMf,
                              float* __restrict__ OUTf, int mode)
{
    const float4* P4   = (const float4*)Pf;
    float4* VSUM       = (float4*)VSUMf;
    float4* OUT        = (float4*)OUTf;
    const int idx = blockIdx.x * blockDim.x + threadIdx.x;   // 0..16383
    float4 v = make_float4(0.f, 0.f, 0.f, 0.f);
#pragma unroll 8
    for (int ig = 0; ig < nparts; ++ig) {
        const float4 p = P4[(size_t)ig * (B_TOT * JD / 4) + idx];
        v.x += p.x; v.y += p.y; v.z += p.z; v.w += p.w;
    }
    float s2 = v.x*v.x + v.y*v.y + v.z*v.z + v.w*v.w;
    s2 += __shfl_xor(s2, 1, 8);
    s2 += __shfl_xor(s2, 2, 8);
    s2 += __shfl_xor(s2, 4, 8);
    const float sc = s2 / (1.f + s2) * rsqrtf(s2 + EPS_SQ);
    float4 o = make_float4(v.x * sc, v.y * sc, v.z * sc, v.w * sc);
    if (mode == 0) {
        VSUM[idx] = o;
    } else if (mode == 1) {
        float4 u = VSUM[idx];
        u.x += o.x; u.y += o.y; u.z += o.z; u.w += o.w;
        VSUM[idx] = u;
    } else {
        OUT[idx] = o;
    }
}

extern "C" void kernel_launch(void* const* d_in, const int* in_sizes, int n_in,
                              void* d_out, int out_size, void* d_ws, size_t ws_size,
                              hipStream_t stream)
{
    const float* x = (const float*)d_in[0];   // [64, 2048, 16]
    const float* W = (const float*)d_in[1];   // [32, 2048, 32, 16]
    float* out = (float*)d_out;               // [64, 32, 32]

    const dim3 grid(N_IG * N_BG);             // 1024 blocks
    const dim3 blk(256);
    const dim3 rgrid(B_TOT * JD / 4 / 256);   // 64 blocks

    const size_t P_elems = (size_t)N_IG * B_TOT * JD;   // 33.6 MB
    const size_t need    = (P_elems + (size_t)B_TOT * JD) * sizeof(float);

    if (ws_size >= need) {
        float* P    = (float*)d_ws;
        float* VSUM = P + P_elems;
        caps_pass<0, 0><<<grid, blk, 0, stream>>>(x, W, nullptr, P);
        reduce_squash<<<rgrid, blk, 0, stream>>>(P, N_IG, VSUM, out, 0);
        caps_pass<1, 0><<<grid, blk, 0, stream>>>(x, W, VSUM, P);
        reduce_squash<<<rgrid, blk, 0, stream>>>(P, N_IG, VSUM, out, 1);
        caps_pass<1, 0><<<grid, blk, 0, stream>>>(x, W, VSUM, P);
        reduce_squash<<<rgrid, blk, 0, stream>>>(P, N_IG, VSUM, out, 2);
    } else {
        float* S    = (float*)d_ws;
        float* VSUM = S + (size_t)B_TOT * JD;
        const size_t sbytes = (size_t)B_TOT * JD * sizeof(float);
        hipMemsetAsync(S, 0, sbytes, stream);
        caps_pass<0, 1><<<grid, blk, 0, stream>>>(x, W, nullptr, S);
        reduce_squash<<<rgrid, blk, 0, stream>>>(S, 1, VSUM, out, 0);
        hipMemsetAsync(S, 0, sbytes, stream);
        caps_pass<1, 1><<<grid, blk, 0, stream>>>(x, W, VSUM, S);
        reduce_squash<<<rgrid, blk, 0, stream>>>(S, 1, VSUM, out, 1);
        hipMemsetAsync(S, 0, sbytes, stream);
        caps_pass<1, 1><<<grid, blk, 0, stream>>>(x, W, VSUM, S);
        reduce_squash<<<rgrid, blk, 0, stream>>>(S, 1, VSUM, out, 2);
    }
}

// Round 5
// 660.258 us; speedup vs baseline: 10.0434x; 10.0434x over previous
//
#include <hip/hip_runtime.h>
#include <math.h>

// CapsuleLayer dynamic routing, MI355X fp32. Round 7: round-5 base + W transpose.
// B=64, In=2048, Din=16, Nc=32, Dc=32, ROUTINGS=3.
// Identity: b starts at 0 => logits_t = hat . (v1+..+v_{t-1}); never store b or hat.
//
// Round-6 post-mortem: LDS-staged W spilled again (WRITE 6GB) + vmcnt(0) drain
// per quarter + 4.3M bank conflicts. Reverted. Round 5 (212us/pass, zero spill)
// is the base. Its two pipe costs: FMA issue ~109us (fixed) and W-load L1
// transactions ~107us (64 lines per wave-instr: private rows at 256B stride).
// Fix the latter only: one-time transpose W -> Wt[i][k4*4+r][j*8+dq] (128MB ws)
// so each W load is lane-contiguous (8 lines/wave-instr, 8x fewer transactions).
// caps_pass structure = round 5 verbatim, templated on TRANS for the W indexing.
// Tiers: ws >= Wt+P -> transposed; ws >= P -> round-5 path; else atomic path.

#define B_TOT   64
#define IN_CAPS 2048
#define DIN     16
#define NC      32
#define DC      32
#define JD      (NC * DC)            // 1024
#define B_CHUNK 8
#define I_CHUNK 16
#define N_IG    (IN_CAPS / I_CHUNK)  // 128
#define N_BG    (B_TOT / B_CHUNK)    // 8
#define EPS_SQ  1e-7f

#define WT_CHUNKS ((size_t)IN_CAPS * 4096)   // 8.4M float4 = 128 MB

__device__ __forceinline__ float dot4(const float4 a, const float4 b) {
    return a.x*b.x + a.y*b.y + a.z*b.z + a.w*b.w;
}

// Raw workgroup barrier: drain LDS ops only (no vmcnt) -> W prefetch survives.
#define LDS_BARRIER() do {                                  \
    asm volatile("" ::: "memory");                          \
    asm volatile("s_waitcnt lgkmcnt(0)");                   \
    __builtin_amdgcn_s_barrier();                           \
    asm volatile("" ::: "memory");                          \
} while (0)

// ---- W transpose: Wt chunk (((i*4+k4)*4+r)*32+j)*8+dq = W[j][i][dq*4+r][k4-quad]
// One block per i. Reads: each thread 16 b128 from its contiguous 256B region
// (2 lines, L1-resident after first touch). Writes: 1KB/wave-instr contiguous.
__global__ void transpose_W(const float* __restrict__ W, float* __restrict__ Wt)
{
    const int i = blockIdx.x;
    const int t = threadIdx.x;               // t = j*8+dq (write ordering)
    const int j = t >> 3, dq = t & 7;
    const float4* Wf = (const float4*)W;
    float4* Wo = (float4*)Wt + (size_t)i * 4096;
    const float4* src = Wf + ((size_t)j * IN_CAPS + i) * 128 + dq * 16;
#pragma unroll
    for (int k4 = 0; k4 < 4; ++k4)
#pragma unroll
        for (int r = 0; r < 4; ++r)
            Wo[(k4 * 4 + r) * 256 + t] = src[r * 4 + k4];
}

// Load one k-quarter (all 4 d-rows at one k4).
// TRANS=0: base = W + (j*IN_CAPS + i0)*128 + doff*4 chunks (round-5 layout).
// TRANS=1: base = Wt + i0*4096 + t chunks (lane-contiguous layout).
template <int TRANS>
__device__ __forceinline__ void wload(float4 (&w)[4], const float4* __restrict__ base,
                                      int il, int k4) {
    if (TRANS) {
        const float4* p = base + (size_t)il * 4096 + k4 * 1024;
        w[0] = p[0];
        w[1] = p[256];
        w[2] = p[512];
        w[3] = p[768];
    } else {
        const float4* p = base + (size_t)il * 128 + k4;
        w[0] = p[0];
        w[1] = p[4];
        w[2] = p[8];
        w[3] = p[12];
    }
}

// One quarter of compute: dst[b][r] (+)= dot(W[row doff+r, k4-quad], x[b, k4-quad])
template <bool ACCUM>
__device__ __forceinline__ void qcomp(const float4 (&w)[4],
                                      const float4 (*__restrict__ xsil)[DIN / 4],
                                      int k4, float (*__restrict__ dst)[4]) {
#pragma unroll
    for (int b = 0; b < B_CHUNK; ++b) {
        const float4 xv = xsil[b][k4];     // block-uniform: LDS broadcast
        if (ACCUM) {
            dst[b][0] += dot4(w[0], xv);
            dst[b][1] += dot4(w[1], xv);
            dst[b][2] += dot4(w[2], xv);
            dst[b][3] += dot4(w[3], xv);
        } else {
            dst[b][0] = dot4(w[0], xv);
            dst[b][1] = dot4(w[1], xv);
            dst[b][2] = dot4(w[2], xv);
            dst[b][3] = dot4(w[3], xv);
        }
    }
}

// PHASE 0: c = 1/32 uniform (softmax of zeros), plain sum.
// PHASE 1: logits = hat . vsum, softmax over j, weighted sum.
template <int PHASE, int ATOMIC, int TRANS>
__launch_bounds__(256, 2)
__global__ void caps_pass(const float* __restrict__ x,
                          const float* __restrict__ Wp,   // W (TRANS=0) or Wt (TRANS=1)
                          const float* __restrict__ vsum,
                          float* __restrict__ P)
{
    __shared__ float4 xs4[I_CHUNK][B_CHUNK][DIN / 4];        // 8 KB
    __shared__ float  c_s[PHASE ? 2 : 1][B_CHUNK][NC];       // 2 KB (phase 1)

    const int t    = threadIdx.x;           // 256 threads
    const int j    = t >> 3;                // 0..31 output capsule
    const int dq   = t & 7;                 // d-quad 0..7
    const int doff = dq * 4;
    const int jd0  = j * DC + doff;

    // XCD-clustered swizzle (round-robin XCD = linear_id % 8):
    // all 8 bg-siblings of one ig occupy consecutive slots on ONE XCD.
    const int r   = blockIdx.x;             // 0..1023
    const int xcd = r & 7;
    const int s   = r >> 3;
    const int bg  = s & 7;
    const int ig  = (s >> 3) * 8 + xcd;
    const int b0  = bg * B_CHUNK;
    const int i0  = ig * I_CHUNK;

    // ---- stage x once (loads issued before W prologue so the ds_write's
    //      vmcnt wait does not drain the W quads) ----
    float4 sx[2];
    int il_s[2], bl_s[2], k4_s[2];
#pragma unroll
    for (int q = 0; q < 2; ++q) {
        const int f = t * 2 + q;            // 512 float4 total
        il_s[q] = f >> 5;
        bl_s[q] = (f >> 2) & 7;
        k4_s[q] = f & 3;
        sx[q] = *(const float4*)
            &x[((size_t)(b0 + bl_s[q]) * IN_CAPS + (i0 + il_s[q])) * DIN + k4_s[q] * 4];
    }

    // W base for this thread
    const float4* base = TRANS
        ? (const float4*)Wp + (size_t)i0 * 4096 + t
        : (const float4*)Wp + ((size_t)j * IN_CAPS + i0) * 128 + doff * 4;

    float4 wE[4], wO[4];
    wload<TRANS>(wE, base, 0, 0);           // prologue: quarter (il=0, k4=0)

#pragma unroll
    for (int q = 0; q < 2; ++q) xs4[il_s[q]][bl_s[q]][k4_s[q]] = sx[q];
    LDS_BARRIER();

    float acc[B_CHUNK][4];
#pragma unroll
    for (int b = 0; b < B_CHUNK; ++b)
#pragma unroll
        for (int dd = 0; dd < 4; ++dd) acc[b][dd] = 0.f;

    float h[B_CHUNK][4];   // phase-1 hat fragments (registers); dead in phase 0
    int buf = 0;

#pragma unroll 1
    for (int il = 0; il < I_CHUNK; ++il) {
        const float4 (*__restrict__ xsil)[DIN / 4] = xs4[il];
        float (*dst)[4] = PHASE ? h : acc;

        // 4 k-quarters, wE/wO ping-pong; next quarter's load issued before the
        // current quarter's compute.
        wload<TRANS>(wO, base, il, 1);
        if (PHASE == 0) qcomp<true >(wE, xsil, 0, acc);
        else            qcomp<false>(wE, xsil, 0, h);
        wload<TRANS>(wE, base, il, 2);
        qcomp<true>(wO, xsil, 1, dst);
        wload<TRANS>(wO, base, il, 3);
        qcomp<true>(wE, xsil, 2, dst);
        if (il + 1 < I_CHUNK) wload<TRANS>(wE, base, il + 1, 0);
        qcomp<true>(wO, xsil, 3, dst);

        if (PHASE == 1) {
            // logits: lp[b] = hat[b] . vsum[b] over this thread's 4 d's (vsum
            // straight from global: 16B/lane coalesced, L2-resident),
            // then reduce over the 8 dq-threads sharing j.
            float lp[B_CHUNK];
#pragma unroll
            for (int b = 0; b < B_CHUNK; ++b) {
                const float4 vv =
                    *(const float4*)&vsum[(size_t)(b0 + b) * JD + jd0];
                lp[b] = h[b][0]*vv.x + h[b][1]*vv.y + h[b][2]*vv.z + h[b][3]*vv.w;
                lp[b] += __shfl_xor(lp[b], 1, 8);
                lp[b] += __shfl_xor(lp[b], 2, 8);
                lp[b] += __shfl_xor(lp[b], 4, 8);
            }
            if (dq == 0) {
#pragma unroll
                for (int b = 0; b < B_CHUNK; ++b) c_s[buf][b][j] = lp[b];
            }
            LDS_BARRIER();

            // softmax over j: one thread per (b, j); width-32 butterflies.
            {
                const int tb = t >> 5, tj = t & 31;
                const float l = c_s[buf][tb][tj];
                float m = l;
                m = fmaxf(m, __shfl_xor(m, 1, 32));
                m = fmaxf(m, __shfl_xor(m, 2, 32));
                m = fmaxf(m, __shfl_xor(m, 4, 32));
                m = fmaxf(m, __shfl_xor(m, 8, 32));
                m = fmaxf(m, __shfl_xor(m, 16, 32));
                const float e = __expf(l - m);
                float ss = e;
                ss += __shfl_xor(ss, 1, 32);
                ss += __shfl_xor(ss, 2, 32);
                ss += __shfl_xor(ss, 4, 32);
                ss += __shfl_xor(ss, 8, 32);
                ss += __shfl_xor(ss, 16, 32);
                c_s[buf][tb][tj] = e / ss;
            }
            LDS_BARRIER();

            // weighted accumulate from register-held hat
#pragma unroll
            for (int b = 0; b < B_CHUNK; ++b) {
                const float c = c_s[buf][b][j];    // broadcast read
                acc[b][0] += c * h[b][0];
                acc[b][1] += c * h[b][1];
                acc[b][2] += c * h[b][2];
                acc[b][3] += c * h[b][3];
            }
            buf ^= 1;   // next il writes the other c_s buffer: no WAR barrier needed
        }
    }

    const float scale = (PHASE == 0) ? (1.f / NC) : 1.f;
    if (ATOMIC) {
#pragma unroll
        for (int b = 0; b < B_CHUNK; ++b) {
            float* dstp = &P[(size_t)(b0 + b) * JD + jd0];
            atomicAdd(dstp + 0, acc[b][0] * scale);
            atomicAdd(dstp + 1, acc[b][1] * scale);
            atomicAdd(dstp + 2, acc[b][2] * scale);
            atomicAdd(dstp + 3, acc[b][3] * scale);
        }
    } else {
        // private partial: P[ig][b_global][jd], coalesced float4 stores
        float* dstp = P + ((size_t)ig * B_TOT + b0) * JD + jd0;
#pragma unroll
        for (int b = 0; b < B_CHUNK; ++b) {
            *(float4*)(dstp + (size_t)b * JD) =
                make_float4(acc[b][0] * scale, acc[b][1] * scale,
                            acc[b][2] * scale, acc[b][3] * scale);
        }
    }
}

// Sum nparts partials (float4), squash over Dc=32 (8 consecutive lanes = one
// capsule), then: mode 0: VSUM = v ; mode 1: VSUM += v ; mode 2: OUT = v
__global__ void reduce_squash(const float* __restrict__ Pf, int nparts,
                              float* __restrict__ VSUMf,
                              float* __restrict__ OUTf, int mode)
{
    const float4* P4   = (const float4*)Pf;
    float4* VSUM       = (float4*)VSUMf;
    float4* OUT        = (float4*)OUTf;
    const int idx = blockIdx.x * blockDim.x + threadIdx.x;   // 0..16383
    float4 v = make_float4(0.f, 0.f, 0.f, 0.f);
#pragma unroll 8
    for (int ig = 0; ig < nparts; ++ig) {
        const float4 p = P4[(size_t)ig * (B_TOT * JD / 4) + idx];
        v.x += p.x; v.y += p.y; v.z += p.z; v.w += p.w;
    }
    float s2 = v.x*v.x + v.y*v.y + v.z*v.z + v.w*v.w;
    s2 += __shfl_xor(s2, 1, 8);
    s2 += __shfl_xor(s2, 2, 8);
    s2 += __shfl_xor(s2, 4, 8);
    const float sc = s2 / (1.f + s2) * rsqrtf(s2 + EPS_SQ);
    float4 o = make_float4(v.x * sc, v.y * sc, v.z * sc, v.w * sc);
    if (mode == 0) {
        VSUM[idx] = o;
    } else if (mode == 1) {
        float4 u = VSUM[idx];
        u.x += o.x; u.y += o.y; u.z += o.z; u.w += o.w;
        VSUM[idx] = u;
    } else {
        OUT[idx] = o;
    }
}

extern "C" void kernel_launch(void* const* d_in, const int* in_sizes, int n_in,
                              void* d_out, int out_size, void* d_ws, size_t ws_size,
                              hipStream_t stream)
{
    const float* x = (const float*)d_in[0];   // [64, 2048, 16]
    const float* W = (const float*)d_in[1];   // [32, 2048, 32, 16]
    float* out = (float*)d_out;               // [64, 32, 32]

    const dim3 grid(N_IG * N_BG);             // 1024 blocks (XCD-swizzled in-kernel)
    const dim3 blk(256);
    const dim3 rgrid(B_TOT * JD / 4 / 256);   // 64 blocks

    const size_t P_elems  = (size_t)N_IG * B_TOT * JD;              // 33.6 MB
    const size_t vs_elems = (size_t)B_TOT * JD;                     // 256 KB
    const size_t need_p   = (P_elems + vs_elems) * sizeof(float);
    const size_t need_t   = (WT_CHUNKS * 4 + P_elems + vs_elems) * sizeof(float);

    if (ws_size >= need_t) {
        // transposed-W path: lane-contiguous W loads (8 lines/wave-instr)
        float* Wt   = (float*)d_ws;
        float* P    = Wt + WT_CHUNKS * 4;
        float* VSUM = P + P_elems;
        transpose_W<<<dim3(IN_CAPS), blk, 0, stream>>>(W, Wt);
        caps_pass<0, 0, 1><<<grid, blk, 0, stream>>>(x, Wt, nullptr, P);
        reduce_squash<<<rgrid, blk, 0, stream>>>(P, N_IG, VSUM, out, 0);
        caps_pass<1, 0, 1><<<grid, blk, 0, stream>>>(x, Wt, VSUM, P);
        reduce_squash<<<rgrid, blk, 0, stream>>>(P, N_IG, VSUM, out, 1);
        caps_pass<1, 0, 1><<<grid, blk, 0, stream>>>(x, Wt, VSUM, P);
        reduce_squash<<<rgrid, blk, 0, stream>>>(P, N_IG, VSUM, out, 2);
    } else if (ws_size >= need_p) {
        // round-5 path (original W layout)
        float* P    = (float*)d_ws;
        float* VSUM = P + P_elems;
        caps_pass<0, 0, 0><<<grid, blk, 0, stream>>>(x, W, nullptr, P);
        reduce_squash<<<rgrid, blk, 0, stream>>>(P, N_IG, VSUM, out, 0);
        caps_pass<1, 0, 0><<<grid, blk, 0, stream>>>(x, W, VSUM, P);
        reduce_squash<<<rgrid, blk, 0, stream>>>(P, N_IG, VSUM, out, 1);
        caps_pass<1, 0, 0><<<grid, blk, 0, stream>>>(x, W, VSUM, P);
        reduce_squash<<<rgrid, blk, 0, stream>>>(P, N_IG, VSUM, out, 2);
    } else {
        // atomic fallback
        float* S    = (float*)d_ws;
        float* VSUM = S + vs_elems;
        const size_t sbytes = vs_elems * sizeof(float);
        hipMemsetAsync(S, 0, sbytes, stream);
        caps_pass<0, 1, 0><<<grid, blk, 0, stream>>>(x, W, nullptr, S);
        reduce_squash<<<rgrid, blk, 0, stream>>>(S, 1, VSUM, out, 0);
        hipMemsetAsync(S, 0, sbytes, stream);
        caps_pass<1, 1, 0><<<grid, blk, 0, stream>>>(x, W, VSUM, S);
        reduce_squash<<<rgrid, blk, 0, stream>>>(S, 1, VSUM, out, 1);
        hipMemsetAsync(S, 0, sbytes, stream);
        caps_pass<1, 1, 0><<<grid, blk, 0, stream>>>(x, W, VSUM, S);
        reduce_squash<<<rgrid, blk, 0, stream>>>(S, 1, VSUM, out, 2);
    }
}

// Round 6
// 626.315 us; speedup vs baseline: 10.5877x; 1.0542x over previous
//
#include <hip/hip_runtime.h>
#include <math.h>

// CapsuleLayer dynamic routing, MI355X fp32. Round 8: scalar-x + fast transpose
// + wide reduce. B=64, In=2048, Din=16, Nc=32, Dc=32, ROUTINGS=3.
// Identity: b starts at 0 => logits_t = hat . (v1+..+v_{t-1}); never store b or hat.
//
// Round-7 post-mortem: transposed W works (212->150us/pass, no spill). Remaining
// caps_pass cost split: FMA ~27us, W-L1 ~14us, x ds_read_b128 stream ~27-41us --
// all broadcast reads of BLOCK-UNIFORM values. This round:
//  1) x via scalar (SGPR) loads -- address is wave-uniform, v_fma takes 1 SGPR
//     operand. xs4 LDS + its barrier deleted; phase 0 is now barrier-free.
//  2) transpose_W rebuilt: old read side touched 128 lines/instr. Now coalesced
//     read -> LDS tile with sigma(c)=c^((c>>4)&7) swizzle (conflict-free both
//     phases) -> coalesced write.
//  3) reduce_squash: 64 -> 256 blocks (4-way ig-slice + LDS combine).
// Kept: k-quarter W ping-pong, XCD-clustered swizzle, lgkm-only barriers in
// phase 1 (W prefetch survives), private-partial P + reduce (no atomics).

#define B_TOT   64
#define IN_CAPS 2048
#define DIN     16
#define NC      32
#define DC      32
#define JD      (NC * DC)            // 1024
#define B_CHUNK 8
#define I_CHUNK 16
#define N_IG    (IN_CAPS / I_CHUNK)  // 128
#define N_BG    (B_TOT / B_CHUNK)    // 8
#define EPS_SQ  1e-7f

#define WT_CHUNKS ((size_t)IN_CAPS * 4096)   // 8.4M float4 = 128 MB

// Raw workgroup barrier: drain LDS ops only (no vmcnt) -> W prefetch survives.
#define LDS_BARRIER() do {                                  \
    asm volatile("" ::: "memory");                          \
    asm volatile("s_waitcnt lgkmcnt(0)");                   \
    __builtin_amdgcn_s_barrier();                           \
    __builtin_amdgcn_sched_barrier(0);                      \
} while (0)

// ---- W transpose: Wt chunk i*4096 + (k4*4+r)*256 + (j*8+dq)
//      = W[j][i][dq*4+r][k4*4..k4*4+3]
// One block per i. Coalesced read (1KB/wave-instr) -> LDS (swizzled) ->
// coalesced write (1KB/wave-instr). sigma(c) = c ^ ((c>>4)&7):
//  store instr q: c=t+256q, low3 ^= (t>>4)&7 -> 8 distinct bank-groups/8 lanes.
//  gather (k4,r): c=j*128+dq*16+r*4+k4, (c>>4)&7 == dq -> low3 covers 0..7 per
//  8-lane group. Both phases conflict-free.
__global__ __launch_bounds__(256) void transpose_W(const float* __restrict__ W,
                                                   float* __restrict__ Wt)
{
    __shared__ float4 tile[4096];            // 64 KB
    const int i = blockIdx.x;
    const int t = threadIdx.x;
    const float4* Wf = (const float4*)W;
    float4 v[16];
#pragma unroll
    for (int q = 0; q < 16; ++q) {
        const int c  = t + 256 * q;
        const int jj = c >> 7, off = c & 127;
        v[q] = Wf[((size_t)jj * IN_CAPS + i) * 128 + off];
    }
#pragma unroll
    for (int q = 0; q < 16; ++q) {
        const int c = t + 256 * q;
        tile[c ^ ((c >> 4) & 7)] = v[q];
    }
    __syncthreads();
    float4* Wo = (float4*)Wt + (size_t)i * 4096;
    const int j = t >> 3, dq = t & 7;
#pragma unroll
    for (int k4 = 0; k4 < 4; ++k4)
#pragma unroll
        for (int r = 0; r < 4; ++r) {
            const int cg = j * 128 + dq * 16 + r * 4 + k4;
            Wo[(k4 * 4 + r) * 256 + t] = tile[cg ^ dq];   // (cg>>4)&7 == dq
        }
}

// Load one k-quarter (all 4 d-rows at one k4).
// TRANS=1: base = Wt + i0*4096 + t chunks (lane-contiguous).
// TRANS=0: base = W + (j*IN_CAPS + i0)*128 + doff*4 chunks (original layout).
template <int TRANS>
__device__ __forceinline__ void wload(float4 (&w)[4], const float4* __restrict__ base,
                                      int il, int k4) {
    if (TRANS) {
        const float4* p = base + (size_t)il * 4096 + k4 * 1024;
        w[0] = p[0];
        w[1] = p[256];
        w[2] = p[512];
        w[3] = p[768];
    } else {
        const float4* p = base + (size_t)il * 128 + k4;
        w[0] = p[0];
        w[1] = p[4];
        w[2] = p[8];
        w[3] = p[12];
    }
}

// One k-quarter of compute. x read via WAVE-UNIFORM address -> scalar loads;
// each v_fma gets one SGPR operand (x component) + VGPR w + VGPR acc.
template <bool ACCUM>
__device__ __forceinline__ void qcomp(const float4 (&w)[4],
                                      const float* __restrict__ xi,
                                      int k4, float (*__restrict__ dst)[4])
{
#pragma unroll
    for (int b = 0; b < B_CHUNK; ++b) {
        const float* xb = xi + (size_t)b * (IN_CAPS * DIN) + k4 * 4;
        const float x0 = xb[0], x1 = xb[1], x2 = xb[2], x3 = xb[3];
#pragma unroll
        for (int r = 0; r < 4; ++r) {
            const float s = w[r].x * x0 + w[r].y * x1 + w[r].z * x2 + w[r].w * x3;
            if (ACCUM) dst[b][r] += s;
            else       dst[b][r] = s;
        }
    }
}

// PHASE 0: c = 1/32 uniform (softmax of zeros), plain sum.
// PHASE 1: logits = hat . vsum, softmax over j, weighted sum.
template <int PHASE, int ATOMIC, int TRANS>
__launch_bounds__(256, 2)
__global__ void caps_pass(const float* __restrict__ x,
                          const float* __restrict__ Wp,   // W (TRANS=0) or Wt (TRANS=1)
                          const float* __restrict__ vsum,
                          float* __restrict__ P)
{
    __shared__ float c_s[PHASE ? 2 : 1][B_CHUNK][NC];       // 2 KB (phase 1)

    const int t    = threadIdx.x;           // 256 threads
    const int j    = t >> 3;                // 0..31 output capsule
    const int dq   = t & 7;                 // d-quad 0..7
    const int doff = dq * 4;
    const int jd0  = j * DC + doff;

    // XCD-clustered swizzle (round-robin XCD = linear_id % 8):
    // all 8 bg-siblings of one ig occupy consecutive slots on ONE XCD.
    const int r   = blockIdx.x;             // 0..1023
    const int xcd = r & 7;
    const int s   = r >> 3;
    const int bg  = s & 7;
    const int ig  = (s >> 3) * 8 + xcd;
    const int b0  = bg * B_CHUNK;
    const int i0  = ig * I_CHUNK;

    // W base for this thread
    const float4* base = TRANS
        ? (const float4*)Wp + (size_t)i0 * 4096 + t
        : (const float4*)Wp + ((size_t)j * IN_CAPS + i0) * 128 + doff * 4;

    float4 wE[4], wO[4];
    wload<TRANS>(wE, base, 0, 0);           // prologue: quarter (il=0, k4=0)

    float acc[B_CHUNK][4];
#pragma unroll
    for (int b = 0; b < B_CHUNK; ++b)
#pragma unroll
        for (int dd = 0; dd < 4; ++dd) acc[b][dd] = 0.f;

    float h[B_CHUNK][4];   // phase-1 hat fragments (registers); dead in phase 0
    int buf = 0;

#pragma unroll 1
    for (int il = 0; il < I_CHUNK; ++il) {
        // wave-uniform x row base for this il (scalar loads inside qcomp)
        const float* xi = x + ((size_t)b0 * IN_CAPS + (i0 + il)) * DIN;
        float (*dst)[4] = PHASE ? h : acc;

        // 4 k-quarters, wE/wO ping-pong; next quarter's load issued before the
        // current quarter's compute.
        wload<TRANS>(wO, base, il, 1);
        if (PHASE == 0) qcomp<true >(wE, xi, 0, acc);
        else            qcomp<false>(wE, xi, 0, h);
        wload<TRANS>(wE, base, il, 2);
        qcomp<true>(wO, xi, 1, dst);
        wload<TRANS>(wO, base, il, 3);
        qcomp<true>(wE, xi, 2, dst);
        if (il + 1 < I_CHUNK) wload<TRANS>(wE, base, il + 1, 0);
        qcomp<true>(wO, xi, 3, dst);

        if (PHASE == 1) {
            // logits: lp[b] = hat[b] . vsum[b] over this thread's 4 d's (vsum
            // from global: 16B/lane coalesced, L2-resident),
            // then reduce over the 8 dq-threads sharing j.
            float lp[B_CHUNK];
#pragma unroll
            for (int b = 0; b < B_CHUNK; ++b) {
                const float4 vv =
                    *(const float4*)&vsum[(size_t)(b0 + b) * JD + jd0];
                lp[b] = h[b][0]*vv.x + h[b][1]*vv.y + h[b][2]*vv.z + h[b][3]*vv.w;
                lp[b] += __shfl_xor(lp[b], 1, 8);
                lp[b] += __shfl_xor(lp[b], 2, 8);
                lp[b] += __shfl_xor(lp[b], 4, 8);
            }
            if (dq == 0) {
#pragma unroll
                for (int b = 0; b < B_CHUNK; ++b) c_s[buf][b][j] = lp[b];
            }
            LDS_BARRIER();

            // softmax over j: one thread per (b, j); width-32 butterflies.
            {
                const int tb = t >> 5, tj = t & 31;
                const float l = c_s[buf][tb][tj];
                float m = l;
                m = fmaxf(m, __shfl_xor(m, 1, 32));
                m = fmaxf(m, __shfl_xor(m, 2, 32));
                m = fmaxf(m, __shfl_xor(m, 4, 32));
                m = fmaxf(m, __shfl_xor(m, 8, 32));
                m = fmaxf(m, __shfl_xor(m, 16, 32));
                const float e = __expf(l - m);
                float ss = e;
                ss += __shfl_xor(ss, 1, 32);
                ss += __shfl_xor(ss, 2, 32);
                ss += __shfl_xor(ss, 4, 32);
                ss += __shfl_xor(ss, 8, 32);
                ss += __shfl_xor(ss, 16, 32);
                c_s[buf][tb][tj] = e / ss;
            }
            LDS_BARRIER();

            // weighted accumulate from register-held hat
#pragma unroll
            for (int b = 0; b < B_CHUNK; ++b) {
                const float c = c_s[buf][b][j];    // broadcast read
                acc[b][0] += c * h[b][0];
                acc[b][1] += c * h[b][1];
                acc[b][2] += c * h[b][2];
                acc[b][3] += c * h[b][3];
            }
            buf ^= 1;   // next il writes the other c_s buffer: no WAR barrier needed
        }
    }

    const float scale = (PHASE == 0) ? (1.f / NC) : 1.f;
    if (ATOMIC) {
#pragma unroll
        for (int b = 0; b < B_CHUNK; ++b) {
            float* dstp = &P[(size_t)(b0 + b) * JD + jd0];
            atomicAdd(dstp + 0, acc[b][0] * scale);
            atomicAdd(dstp + 1, acc[b][1] * scale);
            atomicAdd(dstp + 2, acc[b][2] * scale);
            atomicAdd(dstp + 3, acc[b][3] * scale);
        }
    } else {
        // private partial: P[ig][b_global][jd], coalesced float4 stores
        float* dstp = P + ((size_t)ig * B_TOT + b0) * JD + jd0;
#pragma unroll
        for (int b = 0; b < B_CHUNK; ++b) {
            *(float4*)(dstp + (size_t)b * JD) =
                make_float4(acc[b][0] * scale, acc[b][1] * scale,
                            acc[b][2] * scale, acc[b][3] * scale);
        }
    }
}

// Sum nparts partials, squash over Dc=32, write per mode.
// Grid 256 blocks x 256 thr: block owns 64 float4-idx; thread sums an ig-slice
// (ig = slice, slice+4, ...), LDS-combine 4 slices, wave 0 squashes + stores.
// mode 0: VSUM = v ; 1: VSUM += v ; 2: OUT = v
__global__ __launch_bounds__(256) void reduce_squash(
    const float* __restrict__ Pf, int nparts,
    float* __restrict__ VSUMf, float* __restrict__ OUTf, int mode)
{
    __shared__ float4 sl[4][64];             // 4 KB
    const float4* P4 = (const float4*)Pf;
    const int t = threadIdx.x, i64 = t & 63, slice = t >> 6;
    const int idx = blockIdx.x * 64 + i64;   // 0..16383
    float4 v = make_float4(0.f, 0.f, 0.f, 0.f);
    for (int ig = slice; ig < nparts; ig += 4) {
        const float4 p = P4[(size_t)ig * (B_TOT * JD / 4) + idx];
        v.x += p.x; v.y += p.y; v.z += p.z; v.w += p.w;
    }
    sl[slice][i64] = v;
    __syncthreads();
    if (t < 64) {
        const float4 a = sl[0][t], b = sl[1][t], c = sl[2][t], d = sl[3][t];
        v.x = a.x + b.x + c.x + d.x;
        v.y = a.y + b.y + c.y + d.y;
        v.z = a.z + b.z + c.z + d.z;
        v.w = a.w + b.w + c.w + d.w;
        float s2 = v.x*v.x + v.y*v.y + v.z*v.z + v.w*v.w;
        s2 += __shfl_xor(s2, 1, 8);
        s2 += __shfl_xor(s2, 2, 8);
        s2 += __shfl_xor(s2, 4, 8);
        const float sc = s2 / (1.f + s2) * rsqrtf(s2 + EPS_SQ);
        const int gidx = blockIdx.x * 64 + t;
        float4 o = make_float4(v.x * sc, v.y * sc, v.z * sc, v.w * sc);
        float4* VSUM = (float4*)VSUMf;
        float4* OUT  = (float4*)OUTf;
        if (mode == 0) {
            VSUM[gidx] = o;
        } else if (mode == 1) {
            float4 u = VSUM[gidx];
            u.x += o.x; u.y += o.y; u.z += o.z; u.w += o.w;
            VSUM[gidx] = u;
        } else {
            OUT[gidx] = o;
        }
    }
}

extern "C" void kernel_launch(void* const* d_in, const int* in_sizes, int n_in,
                              void* d_out, int out_size, void* d_ws, size_t ws_size,
                              hipStream_t stream)
{
    const float* x = (const float*)d_in[0];   // [64, 2048, 16]
    const float* W = (const float*)d_in[1];   // [32, 2048, 32, 16]
    float* out = (float*)d_out;               // [64, 32, 32]

    const dim3 grid(N_IG * N_BG);             // 1024 blocks (XCD-swizzled in-kernel)
    const dim3 blk(256);
    const dim3 rgrid(B_TOT * JD / 4 / 64);    // 256 blocks

    const size_t P_elems  = (size_t)N_IG * B_TOT * JD;              // 33.6 MB
    const size_t vs_elems = (size_t)B_TOT * JD;                     // 256 KB
    const size_t need_p   = (P_elems + vs_elems) * sizeof(float);
    const size_t need_t   = (WT_CHUNKS * 4 + P_elems + vs_elems) * sizeof(float);

    if (ws_size >= need_t) {
        // transposed-W path: lane-contiguous W loads (8 lines/wave-instr)
        float* Wt   = (float*)d_ws;
        float* P    = Wt + WT_CHUNKS * 4;
        float* VSUM = P + P_elems;
        transpose_W<<<dim3(IN_CAPS), blk, 0, stream>>>(W, Wt);
        caps_pass<0, 0, 1><<<grid, blk, 0, stream>>>(x, Wt, nullptr, P);
        reduce_squash<<<rgrid, blk, 0, stream>>>(P, N_IG, VSUM, out, 0);
        caps_pass<1, 0, 1><<<grid, blk, 0, stream>>>(x, Wt, VSUM, P);
        reduce_squash<<<rgrid, blk, 0, stream>>>(P, N_IG, VSUM, out, 1);
        caps_pass<1, 0, 1><<<grid, blk, 0, stream>>>(x, Wt, VSUM, P);
        reduce_squash<<<rgrid, blk, 0, stream>>>(P, N_IG, VSUM, out, 2);
    } else if (ws_size >= need_p) {
        // original-W path
        float* P    = (float*)d_ws;
        float* VSUM = P + P_elems;
        caps_pass<0, 0, 0><<<grid, blk, 0, stream>>>(x, W, nullptr, P);
        reduce_squash<<<rgrid, blk, 0, stream>>>(P, N_IG, VSUM, out, 0);
        caps_pass<1, 0, 0><<<grid, blk, 0, stream>>>(x, W, VSUM, P);
        reduce_squash<<<rgrid, blk, 0, stream>>>(P, N_IG, VSUM, out, 1);
        caps_pass<1, 0, 0><<<grid, blk, 0, stream>>>(x, W, VSUM, P);
        reduce_squash<<<rgrid, blk, 0, stream>>>(P, N_IG, VSUM, out, 2);
    } else {
        // atomic fallback
        float* S    = (float*)d_ws;
        float* VSUM = S + vs_elems;
        const size_t sbytes = vs_elems * sizeof(float);
        hipMemsetAsync(S, 0, sbytes, stream);
        caps_pass<0, 1, 0><<<grid, blk, 0, stream>>>(x, W, nullptr, S);
        reduce_squash<<<rgrid, blk, 0, stream>>>(S, 1, VSUM, out, 0);
        hipMemsetAsync(S, 0, sbytes, stream);
        caps_pass<1, 1, 0><<<grid, blk, 0, stream>>>(x, W, VSUM, S);
        reduce_squash<<<rgrid, blk, 0, stream>>>(S, 1, VSUM, out, 1);
        hipMemsetAsync(S, 0, sbytes, stream);
        caps_pass<1, 1, 0><<<grid, blk, 0, stream>>>(x, W, VSUM, S);
        reduce_squash<<<rgrid, blk, 0, stream>>>(S, 1, VSUM, out, 2);
    }
}